// Round 4
// baseline (584.278 us; speedup 1.0000x reference)
//
#include <hip/hip_runtime.h>
#include <math.h>

#define BATCH 64
#define DK 256
#define FEATURES 512
#define NUM_TAPE 2048
#define TOPK 512
#define TOP16 16
#define THRESH 4.0f
#define KCHUNKS 8
#define KPER (TOPK / KCHUNKS) /* 64 */
#define TIECAP 640

// output layout (floats)
#define OFF_Q 0
#define OFF_HP (BATCH * DK)                    /* 16384 */
#define OFF_REM (OFF_HP + BATCH)               /* 16448 */
#define OFF_NUP (OFF_REM + BATCH)              /* 16512 */
#define OFF_MASK (OFF_NUP + BATCH)             /* 16576 */
#define OFF_TSEL (OFF_MASK + BATCH * NUM_TAPE) /* 147648 */

// ws layout (floats)
#define WS_SCORES 0      /* 64*2048 */
#define WS_TOPK 131072   /* int, 64*512 */
#define WS_WEIGHTS 163840
#define WS_PART 196608   /* 64*8*512 */
#define WS_TICK 458752   /* int cnt0[64], cnt1[64] */

__device__ __forceinline__ unsigned f2key(float f) {
    unsigned u = __float_as_uint(f);
    return (u & 0x80000000u) ? ~u : (u | 0x80000000u);
}

// ======== Kernel 1: scores + (last block per batch) radix-select topk =========
__global__ __launch_bounds__(256) void k_scores_topk(
    const float* __restrict__ q, const float* __restrict__ tape,
    const float* __restrict__ mask_in, const float* __restrict__ hp_in,
    const float* __restrict__ rem_in, const float* __restrict__ nup_in,
    float* __restrict__ scores, int* __restrict__ topk_ws, float* __restrict__ weights_ws,
    int* __restrict__ cnt0, float* __restrict__ out) {
    const int b = blockIdx.y;
    const int tid = threadIdx.x;
    const int wave = tid >> 6;
    const int lane = tid & 63;
    __shared__ int sh_win;

    // ---- scores for 32 tokens
    {
        const float4 qf = reinterpret_cast<const float4*>(q + (size_t)b * DK)[lane];
        const int base = blockIdx.x * 32;
#pragma unroll
        for (int t = 0; t < 8; ++t) {
            const int tok = base + wave + 4 * t;
            const float4 tf = reinterpret_cast<const float4*>(
                tape + ((size_t)b * NUM_TAPE + tok) * FEATURES)[lane];
            float s = qf.x * tf.x + qf.y * tf.y + qf.z * tf.z + qf.w * tf.w;
#pragma unroll
            for (int off = 32; off; off >>= 1) s += __shfl_xor(s, off);
            if (lane == 0) scores[b * NUM_TAPE + tok] = s;
        }
    }
    __threadfence();
    __syncthreads();
    if (tid == 0) sh_win = (atomicAdd(&cnt0[b], 1) == 63) ? 1 : 0;
    __syncthreads();
    if (!sh_win) return;
    __threadfence();  // acquire: all 64 blocks' scores for batch b visible

    // softmax below reads scores[0, idx] (jnp.take flatten bug) -> wait batch 0
    if (tid == 0) {
        while (__hip_atomic_load(&cnt0[0], __ATOMIC_ACQUIRE, __HIP_MEMORY_SCOPE_AGENT) < 64) {}
    }
    __syncthreads();
    __threadfence();

    // ---- topk for batch b, 256 threads, 8 keys/thread
    __shared__ int hist[256];
    __shared__ int chunkTot[4];
    __shared__ int sh_digit, sh_hi;
    __shared__ int sel_idx_s[TOPK];
    __shared__ unsigned sel_key_s[TOPK];
    __shared__ float redf[4];
    __shared__ int tie_idx_s[TIECAP];
    __shared__ int tie_cnt, sel_cnt;
    __shared__ int in16_idx_s[TOP16];

    const float4* scp = reinterpret_cast<const float4*>(scores + (size_t)b * NUM_TAPE);
    const float4* mkp = reinterpret_cast<const float4*>(mask_in + (size_t)b * NUM_TAPE);
    const float4 sc0 = scp[2 * tid], sc1 = scp[2 * tid + 1];
    const float4 mk0 = mkp[2 * tid], mk1 = mkp[2 * tid + 1];
    unsigned key[8];
    key[0] = f2key(sc0.x - mk0.x * 1e9f);
    key[1] = f2key(sc0.y - mk0.y * 1e9f);
    key[2] = f2key(sc0.z - mk0.z * 1e9f);
    key[3] = f2key(sc0.w - mk0.w * 1e9f);
    key[4] = f2key(sc1.x - mk1.x * 1e9f);
    key[5] = f2key(sc1.y - mk1.y * 1e9f);
    key[6] = f2key(sc1.z - mk1.z * 1e9f);
    key[7] = f2key(sc1.w - mk1.w * 1e9f);

    // ---- radix select 1: k = 512 over 2048 keys
    unsigned prefix = 0;
    int krem = TOPK;
#pragma unroll
    for (int p = 0; p < 4; ++p) {
        const int shift = 24 - 8 * p;
        hist[tid] = 0;
        __syncthreads();
#pragma unroll
        for (int i = 0; i < 8; ++i) {
            const unsigned kk = key[i];
            const bool act = (p == 0) || ((kk >> (shift + 8)) == (prefix >> (shift + 8)));
            if (act) atomicAdd(&hist[(kk >> shift) & 0xFF], 1);
        }
        __syncthreads();
        const int hcnt = hist[tid];
        int v = hcnt;
#pragma unroll
        for (int off = 1; off < 64; off <<= 1) {
            const int t = __shfl_down(v, off);
            if (lane + off < 64) v += t;
        }
        if (lane == 0) chunkTot[wave] = v;
        __syncthreads();
#pragma unroll
        for (int w2 = 0; w2 < 4; ++w2)
            if (w2 > wave) v += chunkTot[w2];
        if (v >= krem && (v - hcnt) < krem) {
            sh_digit = tid;
            sh_hi = v - hcnt;
        }
        __syncthreads();
        prefix |= ((unsigned)sh_digit) << shift;
        krem -= sh_hi;
        __syncthreads();
    }
    const unsigned T512 = prefix;
    const int krem512 = krem;

    // ---- compaction: key > T512 plus first krem512 ties (ascending index)
    if (tid == 0) {
        sel_cnt = 0;
        tie_cnt = 0;
    }
    __syncthreads();
#pragma unroll
    for (int i = 0; i < 8; ++i) {
        const int e = 8 * tid + i;
        const unsigned kk = key[i];
        if (kk > T512) {
            const int p = atomicAdd(&sel_cnt, 1);
            sel_idx_s[p] = e;
            sel_key_s[p] = kk;
        } else if (kk == T512) {
            const int p = atomicAdd(&tie_cnt, 1);
            if (p < TIECAP) tie_idx_s[p] = e;
        }
    }
    __syncthreads();
    int tc = tie_cnt < TIECAP ? tie_cnt : TIECAP;
    for (int t = tid; t < tc; t += 256) {
        const int my = tie_idx_s[t];
        int rank = 0;
        for (int u = 0; u < tc; ++u) rank += (tie_idx_s[u] < my);
        if (rank < krem512) {
            const int p = atomicAdd(&sel_cnt, 1);
            sel_idx_s[p] = my;
            sel_key_s[p] = T512;
        }
    }
    __syncthreads();

    // ---- radix select 2: k = 16 over the 512 selected keys (2/thread)
    const unsigned kk2a = sel_key_s[tid];
    const unsigned kk2b = sel_key_s[tid + 256];
    prefix = 0;
    krem = TOP16;
#pragma unroll
    for (int p = 0; p < 4; ++p) {
        const int shift = 24 - 8 * p;
        hist[tid] = 0;
        __syncthreads();
        {
            bool act = (p == 0) || ((kk2a >> (shift + 8)) == (prefix >> (shift + 8)));
            if (act) atomicAdd(&hist[(kk2a >> shift) & 0xFF], 1);
            act = (p == 0) || ((kk2b >> (shift + 8)) == (prefix >> (shift + 8)));
            if (act) atomicAdd(&hist[(kk2b >> shift) & 0xFF], 1);
        }
        __syncthreads();
        const int hcnt = hist[tid];
        int v = hcnt;
#pragma unroll
        for (int off = 1; off < 64; off <<= 1) {
            const int t = __shfl_down(v, off);
            if (lane + off < 64) v += t;
        }
        if (lane == 0) chunkTot[wave] = v;
        __syncthreads();
#pragma unroll
        for (int w2 = 0; w2 < 4; ++w2)
            if (w2 > wave) v += chunkTot[w2];
        if (v >= krem && (v - hcnt) < krem) {
            sh_digit = tid;
            sh_hi = v - hcnt;
        }
        __syncthreads();
        prefix |= ((unsigned)sh_digit) << shift;
        krem -= sh_hi;
        __syncthreads();
    }
    const unsigned T16 = prefix;
    const int krem16 = krem;

    // ---- top16 boundary-tie membership (ascending original index)
    if (tid == 0) tie_cnt = 0;
    __syncthreads();
    if (kk2a == T16) {
        const int p = atomicAdd(&tie_cnt, 1);
        if (p < TIECAP) tie_idx_s[p] = sel_idx_s[tid];
    }
    if (kk2b == T16) {
        const int p = atomicAdd(&tie_cnt, 1);
        if (p < TIECAP) tie_idx_s[p] = sel_idx_s[tid + 256];
    }
    __syncthreads();
    tc = tie_cnt < TIECAP ? tie_cnt : TIECAP;
    for (int t = tid; t < tc; t += 256) {
        const int my = tie_idx_s[t];
        int rank = 0;
        for (int u = 0; u < tc; ++u) rank += (tie_idx_s[u] < my);
        if (rank < krem16) in16_idx_s[rank] = my;
    }
    __syncthreads();

    // ---- softmax over row-0 scores at selected idx (flatten semantics)
    const int idxa = sel_idx_s[tid];
    const int idxb = sel_idx_s[tid + 256];
    const float wra = scores[idxa] * 0.0625f;
    const float wrb = scores[idxb] * 0.0625f;

    float m = fmaxf(wra, wrb);
#pragma unroll
    for (int off = 32; off; off >>= 1) m = fmaxf(m, __shfl_xor(m, off));
    if (lane == 0) redf[wave] = m;
    __syncthreads();
    m = fmaxf(fmaxf(redf[0], redf[1]), fmaxf(redf[2], redf[3]));
    __syncthreads();

    const float ea = expf(wra - m);
    const float eb = expf(wrb - m);
    float s = ea + eb;
#pragma unroll
    for (int off = 32; off; off >>= 1) s += __shfl_xor(s, off);
    if (lane == 0) redf[wave] = s;
    __syncthreads();
    s = (redf[0] + redf[1]) + (redf[2] + redf[3]);
    __syncthreads();

    const float wa = ea / s;
    const float wb = eb / s;
    weights_ws[b * TOPK + tid] = wa;
    weights_ws[b * TOPK + tid + 256] = wb;
    topk_ws[b * TOPK + tid] = idxa;
    topk_ws[b * TOPK + tid + 256] = idxb;

    float lsq = wa * wa + wb * wb;
#pragma unroll
    for (int off = 32; off; off >>= 1) lsq += __shfl_xor(lsq, off);
    if (lane == 0) redf[wave] = lsq;
    __syncthreads();
    const float sumsq = (redf[0] + redf[1]) + (redf[2] + redf[3]);
    __syncthreads();

    bool in16a = (kk2a > T16);
    bool in16b = (kk2b > T16);
    if (kk2a == T16)
        for (int u = 0; u < krem16; ++u)
            if (in16_idx_s[u] == idxa) in16a = true;
    if (kk2b == T16)
        for (int u = 0; u < krem16; ++u)
            if (in16_idx_s[u] == idxb) in16b = true;
    float l16 = (in16a ? wa : 0.f) + (in16b ? wb : 0.f);
#pragma unroll
    for (int off = 32; off; off >>= 1) l16 += __shfl_xor(l16, off);
    if (lane == 0) redf[wave] = l16;
    __syncthreads();
    const float s16 = (redf[0] + redf[1]) + (redf[2] + redf[3]);

    if (tid == 0) {
        const float hp = hp_in[b], rem = rem_in[b], nup = nup_in[b];
        const float entropy = 1.0f - sumsq;
        const float still = (hp < THRESH) ? 1.f : 0.f;
        const float nh = ((hp + s16) >= THRESH ? 1.f : 0.f) * still;
        const float st2 = still - nh;
        out[OFF_REM + b] = rem + (nh + st2) * entropy;
        float hp1 = hp + s16 * st2;
        hp1 = hp1 + nh * (THRESH - hp1);
        out[OFF_HP + b] = hp1;
        out[OFF_NUP + b] = nup + st2 + nh;
    }

    // ---- score_mask: copy row, then +1 at selected
    float4* mout = reinterpret_cast<float4*>(out + OFF_MASK + (size_t)b * NUM_TAPE);
    mout[2 * tid] = mk0;
    mout[2 * tid + 1] = mk1;
    __syncthreads();
    out[OFF_MASK + b * NUM_TAPE + idxa] = mask_in[b * NUM_TAPE + idxa] + 1.0f;
    out[OFF_MASK + b * NUM_TAPE + idxb] = mask_in[b * NUM_TAPE + idxb] + 1.0f;
}

// ======== Kernel 2: gather partials + (last chunk per batch) finish ==========
__global__ __launch_bounds__(512) void k_gather_finish(
    const float* __restrict__ tape, const int* __restrict__ topk_ws,
    const float* __restrict__ weights_ws, const float* __restrict__ q,
    float* __restrict__ partials, int* __restrict__ cnt1, float* __restrict__ out) {
    const int b = blockIdx.y;
    const int kc = blockIdx.x;
    const int tid = threadIdx.x;
    const int rs = tid >> 7;   // 0..3 row-subgroup
    const int f4 = tid & 127;  // float4 feature index
    __shared__ float wsh[KPER];
    __shared__ int ish[KPER];
    __shared__ float4 shacc[512];
    __shared__ int sh_win;
    if (tid < KPER) {
        wsh[tid] = weights_ws[b * TOPK + kc * KPER + tid];
        ish[tid] = topk_ws[b * TOPK + kc * KPER + tid];
    }
    __syncthreads();
    float4 acc = {0.f, 0.f, 0.f, 0.f};
#pragma unroll 4
    for (int k = rs; k < KPER; k += 4) {
        const float w = wsh[k];
        const float4 t =
            reinterpret_cast<const float4*>(tape + ((size_t)b * NUM_TAPE + ish[k]) * FEATURES)[f4];
        acc.x = fmaf(w, t.x, acc.x);
        acc.y = fmaf(w, t.y, acc.y);
        acc.z = fmaf(w, t.z, acc.z);
        acc.w = fmaf(w, t.w, acc.w);
    }
    shacc[tid] = acc;
    __syncthreads();
    if (tid < 128) {
        const float4 a0 = shacc[f4];
        const float4 a1 = shacc[128 + f4];
        const float4 a2 = shacc[256 + f4];
        const float4 a3 = shacc[384 + f4];
        float4 r;
        r.x = (a0.x + a1.x) + (a2.x + a3.x);
        r.y = (a0.y + a1.y) + (a2.y + a3.y);
        r.z = (a0.z + a1.z) + (a2.z + a3.z);
        r.w = (a0.w + a1.w) + (a2.w + a3.w);
        reinterpret_cast<float4*>(partials + ((size_t)b * KCHUNKS + kc) * FEATURES)[f4] = r;
    }
    __threadfence();
    __syncthreads();
    if (tid == 0) sh_win = (atomicAdd(&cnt1[b], 1) == KCHUNKS - 1) ? 1 : 0;
    __syncthreads();
    if (!sh_win) return;
    __threadfence();  // acquire: all 8 chunk partials for batch b visible

    // ---- finish: reduce 8 partials -> token_sel + query update
    const float4* pp = reinterpret_cast<const float4*>(partials + (size_t)b * KCHUNKS * FEATURES);
    const int g = tid >> 7;
    const float4 a = pp[g * 128 + f4];
    const float4 c = pp[(g + 4) * 128 + f4];
    float4 r;
    r.x = a.x + c.x;
    r.y = a.y + c.y;
    r.z = a.z + c.z;
    r.w = a.w + c.w;
    shacc[tid] = r;
    __syncthreads();
    if (tid < 128) {
        const float4 s0 = shacc[f4];
        const float4 s1 = shacc[128 + f4];
        const float4 s2 = shacc[256 + f4];
        const float4 s3 = shacc[384 + f4];
        float4 sS;
        sS.x = (s0.x + s1.x) + (s2.x + s3.x);
        sS.y = (s0.y + s1.y) + (s2.y + s3.y);
        sS.z = (s0.z + s1.z) + (s2.z + s3.z);
        sS.w = (s0.w + s1.w) + (s2.w + s3.w);
        reinterpret_cast<float4*>(out + OFF_TSEL + (size_t)b * FEATURES)[f4] = sS;
        if (f4 < 64) {
            const float4 qv = reinterpret_cast<const float4*>(q + (size_t)b * DK)[f4];
            float4 nq;
            nq.x = (qv.x + sS.x) * 0.5f;
            nq.y = (qv.y + sS.y) * 0.5f;
            nq.z = (qv.z + sS.z) * 0.5f;
            nq.w = (qv.w + sS.w) * 0.5f;
            reinterpret_cast<float4*>(out + OFF_Q + (size_t)b * DK)[f4] = nq;
        }
    }
}

extern "C" void kernel_launch(void* const* d_in, const int* in_sizes, int n_in,
                              void* d_out, int out_size, void* d_ws, size_t ws_size,
                              hipStream_t stream) {
    const float* q = (const float*)d_in[0];
    const float* hp = (const float*)d_in[1];
    const float* rem = (const float*)d_in[2];
    const float* nup = (const float*)d_in[3];
    const float* mask = (const float*)d_in[4];
    const float* tape = (const float*)d_in[5];
    float* out = (float*)d_out;
    float* ws = (float*)d_ws;

    float* scores = ws + WS_SCORES;
    int* topk = (int*)(ws + WS_TOPK);
    float* weights = ws + WS_WEIGHTS;
    float* partials = ws + WS_PART;
    int* cnt0 = (int*)(ws + WS_TICK);
    int* cnt1 = cnt0 + BATCH;

    hipMemsetAsync(cnt0, 0, 2 * BATCH * sizeof(int), stream);
    k_scores_topk<<<dim3(NUM_TAPE / 32, BATCH), 256, 0, stream>>>(
        q, tape, mask, hp, rem, nup, scores, topk, weights, cnt0, out);
    k_gather_finish<<<dim3(KCHUNKS, BATCH), 512, 0, stream>>>(
        tape, topk, weights, q, partials, cnt1, out);
}

// Round 5
// 159.554 us; speedup vs baseline: 3.6620x; 3.6620x over previous
//
#include <hip/hip_runtime.h>
#include <math.h>

#define BATCH 64
#define DK 256
#define FEATURES 512
#define NUM_TAPE 2048
#define TOPK 512
#define TOP16 16
#define THRESH 4.0f
#define KCHUNKS 8
#define KPER (TOPK / KCHUNKS) /* 64 */
#define TIECAP 640

// output layout (floats)
#define OFF_Q 0
#define OFF_HP (BATCH * DK)                    /* 16384 */
#define OFF_REM (OFF_HP + BATCH)               /* 16448 */
#define OFF_NUP (OFF_REM + BATCH)              /* 16512 */
#define OFF_MASK (OFF_NUP + BATCH)             /* 16576 */
#define OFF_TSEL (OFF_MASK + BATCH * NUM_TAPE) /* 147648 */

// ws layout (floats)
#define WS_SCORES 0      /* 64*2048 */
#define WS_TOPK 131072   /* int, 64*512 */
#define WS_WEIGHTS 163840
#define WS_PART 196608   /* 64*8*512 */
#define WS_TICK 458752   /* int cnt1[64] */

__device__ __forceinline__ unsigned f2key(float f) {
    unsigned u = __float_as_uint(f);
    return (u & 0x80000000u) ? ~u : (u | 0x80000000u);
}

// ---------------- Kernel A: scores[b][n] = dot(q[b,:256], tape[b,n,:256]) ----------
__global__ __launch_bounds__(256) void k_scores(const float* __restrict__ q,
                                                const float* __restrict__ tape,
                                                float* __restrict__ scores) {
    const int b = blockIdx.y;
    const int wave = threadIdx.x >> 6;
    const int lane = threadIdx.x & 63;
    const float4 qf = reinterpret_cast<const float4*>(q + b * DK)[lane];
    const int base = blockIdx.x * 32;
#pragma unroll
    for (int t = 0; t < 8; ++t) {
        const int tok = base + wave + 4 * t;
        const float4 tf =
            reinterpret_cast<const float4*>(tape + ((size_t)b * NUM_TAPE + tok) * FEATURES)[lane];
        float s = qf.x * tf.x + qf.y * tf.y + qf.z * tf.z + qf.w * tf.w;
#pragma unroll
        for (int off = 32; off; off >>= 1) s += __shfl_xor(s, off);
        if (lane == 0) scores[b * NUM_TAPE + tok] = s;
    }
}

// ---------------- Kernel B: per-batch radix-select top-k + softmax + scalars --------
__global__ __launch_bounds__(512) void k_topk(const float* __restrict__ scores,
                                              const float* __restrict__ mask_in,
                                              const float* __restrict__ hp_in,
                                              const float* __restrict__ rem_in,
                                              const float* __restrict__ nup_in,
                                              int* __restrict__ topk_ws,
                                              float* __restrict__ weights_ws,
                                              float* __restrict__ out) {
    const int b = blockIdx.x;
    const int tid = threadIdx.x;
    const int lane = tid & 63;
    const int wv = tid >> 6;
    __shared__ int hist[256];
    __shared__ int chunkTot[4];
    __shared__ int sh_digit, sh_hi;
    __shared__ int sel_idx[TOPK];
    __shared__ unsigned sel_key[TOPK];
    __shared__ float redf[8];
    __shared__ int tie_idx[TIECAP];
    __shared__ int tie_cnt, sel_cnt;
    __shared__ int in16_idx[TOP16];

    // 4 elements per thread, float4-coalesced: e = 4*tid + j
    const float4 sc = reinterpret_cast<const float4*>(scores + (size_t)b * NUM_TAPE)[tid];
    const float4 mk = reinterpret_cast<const float4*>(mask_in + (size_t)b * NUM_TAPE)[tid];
    unsigned key[4];
    key[0] = f2key(sc.x - mk.x * 1e9f);
    key[1] = f2key(sc.y - mk.y * 1e9f);
    key[2] = f2key(sc.z - mk.z * 1e9f);
    key[3] = f2key(sc.w - mk.w * 1e9f);

    // ---- radix select 1: k = 512 over 2048 keys
    unsigned prefix = 0;
    int krem = TOPK;
#pragma unroll
    for (int p = 0; p < 4; ++p) {
        const int shift = 24 - 8 * p;
        if (tid < 256) hist[tid] = 0;
        __syncthreads();
#pragma unroll
        for (int i = 0; i < 4; ++i) {
            const unsigned kk = key[i];
            const bool act = (p == 0) || ((kk >> (shift + 8)) == (prefix >> (shift + 8)));
            if (act) atomicAdd(&hist[(kk >> shift) & 0xFF], 1);
        }
        __syncthreads();
        int v = 0, hcnt = 0;
        if (tid < 256) {
            hcnt = hist[tid];
            v = hcnt;
#pragma unroll
            for (int off = 1; off < 64; off <<= 1) {
                const int t = __shfl_down(v, off);
                if (lane + off < 64) v += t;
            }
            if (lane == 0) chunkTot[wv] = v;
        }
        __syncthreads();
        if (tid < 256) {
#pragma unroll
            for (int w2 = 0; w2 < 4; ++w2)
                if (w2 > wv) v += chunkTot[w2];
            if (v >= krem && (v - hcnt) < krem) {
                sh_digit = tid;
                sh_hi = v - hcnt;
            }
        }
        __syncthreads();
        prefix |= ((unsigned)sh_digit) << shift;
        krem -= sh_hi;
        __syncthreads();
    }
    const unsigned T512 = prefix;
    const int krem512 = krem;

    // ---- compaction: key > T512 plus first krem512 ties (ascending index)
    if (tid == 0) {
        sel_cnt = 0;
        tie_cnt = 0;
    }
    __syncthreads();
#pragma unroll
    for (int i = 0; i < 4; ++i) {
        const int e = 4 * tid + i;
        const unsigned kk = key[i];
        if (kk > T512) {
            const int p = atomicAdd(&sel_cnt, 1);
            sel_idx[p] = e;
            sel_key[p] = kk;
        } else if (kk == T512) {
            const int p = atomicAdd(&tie_cnt, 1);
            if (p < TIECAP) tie_idx[p] = e;
        }
    }
    __syncthreads();
    int tc = tie_cnt < TIECAP ? tie_cnt : TIECAP;
    for (int t = tid; t < tc; t += 512) {
        const int my = tie_idx[t];
        int rank = 0;
        for (int u = 0; u < tc; ++u) rank += (tie_idx[u] < my);
        if (rank < krem512) {
            const int p = atomicAdd(&sel_cnt, 1);
            sel_idx[p] = my;
            sel_key[p] = T512;
        }
    }
    __syncthreads();

    // ---- radix select 2: k = 16 over the 512 selected keys (1/thread)
    const unsigned kk2 = sel_key[tid];
    prefix = 0;
    krem = TOP16;
#pragma unroll
    for (int p = 0; p < 4; ++p) {
        const int shift = 24 - 8 * p;
        if (tid < 256) hist[tid] = 0;
        __syncthreads();
        {
            const bool act = (p == 0) || ((kk2 >> (shift + 8)) == (prefix >> (shift + 8)));
            if (act) atomicAdd(&hist[(kk2 >> shift) & 0xFF], 1);
        }
        __syncthreads();
        int v = 0, hcnt = 0;
        if (tid < 256) {
            hcnt = hist[tid];
            v = hcnt;
#pragma unroll
            for (int off = 1; off < 64; off <<= 1) {
                const int t = __shfl_down(v, off);
                if (lane + off < 64) v += t;
            }
            if (lane == 0) chunkTot[wv] = v;
        }
        __syncthreads();
        if (tid < 256) {
#pragma unroll
            for (int w2 = 0; w2 < 4; ++w2)
                if (w2 > wv) v += chunkTot[w2];
            if (v >= krem && (v - hcnt) < krem) {
                sh_digit = tid;
                sh_hi = v - hcnt;
            }
        }
        __syncthreads();
        prefix |= ((unsigned)sh_digit) << shift;
        krem -= sh_hi;
        __syncthreads();
    }
    const unsigned T16 = prefix;
    const int krem16 = krem;

    // ---- top16 boundary-tie membership (ascending original index)
    if (tid == 0) tie_cnt = 0;
    __syncthreads();
    if (kk2 == T16) {
        const int p = atomicAdd(&tie_cnt, 1);
        if (p < TIECAP) tie_idx[p] = sel_idx[tid];
    }
    __syncthreads();
    tc = tie_cnt < TIECAP ? tie_cnt : TIECAP;
    for (int t = tid; t < tc; t += 512) {
        const int my = tie_idx[t];
        int rank = 0;
        for (int u = 0; u < tc; ++u) rank += (tie_idx[u] < my);
        if (rank < krem16) in16_idx[rank] = my;
    }
    __syncthreads();

    // ---- softmax over row-0 scores at selected idx (jnp.take flatten semantics)
    const int myidx = sel_idx[tid];
    const float wraw = scores[myidx] * 0.0625f; // scores[0, idx] / sqrt(256)

    float m = wraw;
#pragma unroll
    for (int off = 32; off; off >>= 1) m = fmaxf(m, __shfl_xor(m, off));
    if (lane == 0) redf[wv] = m;
    __syncthreads();
#pragma unroll
    for (int w2 = 0; w2 < 8; ++w2) m = fmaxf(m, redf[w2]);
    __syncthreads();

    const float e = expf(wraw - m);
    float s = e;
#pragma unroll
    for (int off = 32; off; off >>= 1) s += __shfl_xor(s, off);
    if (lane == 0) redf[wv] = s;
    __syncthreads();
    s = 0.f;
#pragma unroll
    for (int w2 = 0; w2 < 8; ++w2) s += redf[w2];
    __syncthreads();

    const float w = e / s;
    weights_ws[b * TOPK + tid] = w;
    topk_ws[b * TOPK + tid] = myidx;

    float lsq = w * w;
#pragma unroll
    for (int off = 32; off; off >>= 1) lsq += __shfl_xor(lsq, off);
    if (lane == 0) redf[wv] = lsq;
    __syncthreads();
    float sumsq = 0.f;
#pragma unroll
    for (int w2 = 0; w2 < 8; ++w2) sumsq += redf[w2];
    __syncthreads();

    bool in16 = (kk2 > T16);
    if (kk2 == T16) {
        for (int u = 0; u < krem16; ++u)
            if (in16_idx[u] == myidx) in16 = true;
    }
    float l16 = in16 ? w : 0.f;
#pragma unroll
    for (int off = 32; off; off >>= 1) l16 += __shfl_xor(l16, off);
    if (lane == 0) redf[wv] = l16;
    __syncthreads();
    float s16 = 0.f;
#pragma unroll
    for (int w2 = 0; w2 < 8; ++w2) s16 += redf[w2];

    if (tid == 0) {
        const float hp = hp_in[b], rem = rem_in[b], nup = nup_in[b];
        const float entropy = 1.0f - sumsq;
        const float still = (hp < THRESH) ? 1.f : 0.f;
        const float nh = ((hp + s16) >= THRESH ? 1.f : 0.f) * still;
        const float st2 = still - nh;
        out[OFF_REM + b] = rem + (nh + st2) * entropy;
        float hp1 = hp + s16 * st2;
        hp1 = hp1 + nh * (THRESH - hp1);
        out[OFF_HP + b] = hp1;
        out[OFF_NUP + b] = nup + st2 + nh;
    }

    // score_mask: copy row (we already hold it as mk), then +1 at selected
    reinterpret_cast<float4*>(out + OFF_MASK + (size_t)b * NUM_TAPE)[tid] = mk;
    __syncthreads();
    out[OFF_MASK + b * NUM_TAPE + myidx] = mask_in[b * NUM_TAPE + myidx] + 1.0f;
}

// ======== Kernel C: gather partials + (last chunk per batch) finish ==========
__global__ __launch_bounds__(512) void k_gather_finish(
    const float* __restrict__ tape, const int* __restrict__ topk_ws,
    const float* __restrict__ weights_ws, const float* __restrict__ q,
    float* __restrict__ partials, int* __restrict__ cnt1, float* __restrict__ out) {
    const int b = blockIdx.y;
    const int kc = blockIdx.x;
    const int tid = threadIdx.x;
    const int rs = tid >> 7;   // 0..3 row-subgroup
    const int f4 = tid & 127;  // float4 feature index
    __shared__ float wsh[KPER];
    __shared__ int ish[KPER];
    __shared__ float4 shacc[512];
    __shared__ int sh_win;
    if (tid < KPER) {
        wsh[tid] = weights_ws[b * TOPK + kc * KPER + tid];
        ish[tid] = topk_ws[b * TOPK + kc * KPER + tid];
    }
    __syncthreads();
    float4 acc = {0.f, 0.f, 0.f, 0.f};
#pragma unroll 4
    for (int k = rs; k < KPER; k += 4) {
        const float w = wsh[k];
        const float4 t =
            reinterpret_cast<const float4*>(tape + ((size_t)b * NUM_TAPE + ish[k]) * FEATURES)[f4];
        acc.x = fmaf(w, t.x, acc.x);
        acc.y = fmaf(w, t.y, acc.y);
        acc.z = fmaf(w, t.z, acc.z);
        acc.w = fmaf(w, t.w, acc.w);
    }
    shacc[tid] = acc;
    __syncthreads();
    if (tid < 128) {
        const float4 a0 = shacc[f4];
        const float4 a1 = shacc[128 + f4];
        const float4 a2 = shacc[256 + f4];
        const float4 a3 = shacc[384 + f4];
        float4 r;
        r.x = (a0.x + a1.x) + (a2.x + a3.x);
        r.y = (a0.y + a1.y) + (a2.y + a3.y);
        r.z = (a0.z + a1.z) + (a2.z + a3.z);
        r.w = (a0.w + a1.w) + (a2.w + a3.w);
        reinterpret_cast<float4*>(partials + ((size_t)b * KCHUNKS + kc) * FEATURES)[f4] = r;
    }
    __threadfence();
    __syncthreads();
    if (tid == 0) sh_win = (atomicAdd(&cnt1[b], 1) == KCHUNKS - 1) ? 1 : 0;
    __syncthreads();
    if (!sh_win) return;
    __threadfence();  // acquire: all 8 chunk partials for batch b visible

    // ---- finish: reduce 8 partials -> token_sel + query update
    const float4* pp = reinterpret_cast<const float4*>(partials + (size_t)b * KCHUNKS * FEATURES);
    const int g = tid >> 7;
    const float4 a = pp[g * 128 + f4];
    const float4 c = pp[(g + 4) * 128 + f4];
    float4 r;
    r.x = a.x + c.x;
    r.y = a.y + c.y;
    r.z = a.z + c.z;
    r.w = a.w + c.w;
    shacc[tid] = r;
    __syncthreads();
    if (tid < 128) {
        const float4 s0 = shacc[f4];
        const float4 s1 = shacc[128 + f4];
        const float4 s2 = shacc[256 + f4];
        const float4 s3 = shacc[384 + f4];
        float4 sS;
        sS.x = (s0.x + s1.x) + (s2.x + s3.x);
        sS.y = (s0.y + s1.y) + (s2.y + s3.y);
        sS.z = (s0.z + s1.z) + (s2.z + s3.z);
        sS.w = (s0.w + s1.w) + (s2.w + s3.w);
        reinterpret_cast<float4*>(out + OFF_TSEL + (size_t)b * FEATURES)[f4] = sS;
        if (f4 < 64) {
            const float4 qv = reinterpret_cast<const float4*>(q + (size_t)b * DK)[f4];
            float4 nq;
            nq.x = (qv.x + sS.x) * 0.5f;
            nq.y = (qv.y + sS.y) * 0.5f;
            nq.z = (qv.z + sS.z) * 0.5f;
            nq.w = (qv.w + sS.w) * 0.5f;
            reinterpret_cast<float4*>(out + OFF_Q + (size_t)b * DK)[f4] = nq;
        }
    }
}

extern "C" void kernel_launch(void* const* d_in, const int* in_sizes, int n_in,
                              void* d_out, int out_size, void* d_ws, size_t ws_size,
                              hipStream_t stream) {
    const float* q = (const float*)d_in[0];
    const float* hp = (const float*)d_in[1];
    const float* rem = (const float*)d_in[2];
    const float* nup = (const float*)d_in[3];
    const float* mask = (const float*)d_in[4];
    const float* tape = (const float*)d_in[5];
    float* out = (float*)d_out;
    float* ws = (float*)d_ws;

    float* scores = ws + WS_SCORES;
    int* topk = (int*)(ws + WS_TOPK);
    float* weights = ws + WS_WEIGHTS;
    float* partials = ws + WS_PART;
    int* cnt1 = (int*)(ws + WS_TICK);

    hipMemsetAsync(cnt1, 0, BATCH * sizeof(int), stream);
    k_scores<<<dim3(NUM_TAPE / 32, BATCH), 256, 0, stream>>>(q, tape, scores);
    k_topk<<<BATCH, 512, 0, stream>>>(scores, mask, hp, rem, nup, topk, weights, out);
    k_gather_finish<<<dim3(KCHUNKS, BATCH), 512, 0, stream>>>(
        tape, topk, weights, q, partials, cnt1, out);
}

// Round 6
// 50.601 us; speedup vs baseline: 11.5467x; 3.1531x over previous
//
#include <hip/hip_runtime.h>
#include <math.h>

#define BATCH 64
#define DK 256
#define FEATURES 512
#define NUM_TAPE 2048
#define TOPK 512
#define TOP16 16
#define THRESH 4.0f
#define KCHUNKS 8
#define KPER (TOPK / KCHUNKS) /* 64 */
#define TIECAP 640

// output layout (floats)
#define OFF_Q 0
#define OFF_HP (BATCH * DK)                    /* 16384 */
#define OFF_REM (OFF_HP + BATCH)               /* 16448 */
#define OFF_NUP (OFF_REM + BATCH)              /* 16512 */
#define OFF_MASK (OFF_NUP + BATCH)             /* 16576 */
#define OFF_TSEL (OFF_MASK + BATCH * NUM_TAPE) /* 147648 */

// ws layout (floats)
#define WS_SCORES 0      /* 64*2048 */
#define WS_TOPK 131072   /* int, 64*512 */
#define WS_WEIGHTS 163840
#define WS_PART 196608 /* 64*8*512 */

__device__ __forceinline__ unsigned f2key(float f) {
    unsigned u = __float_as_uint(f);
    return (u & 0x80000000u) ? ~u : (u | 0x80000000u);
}

// ---------------- Kernel A: scores[b][n] = dot(q[b,:256], tape[b,n,:256]) ----------
__global__ __launch_bounds__(256) void k_scores(const float* __restrict__ q,
                                                const float* __restrict__ tape,
                                                float* __restrict__ scores) {
    const int b = blockIdx.y;
    const int wave = threadIdx.x >> 6;
    const int lane = threadIdx.x & 63;
    const float4 qf = reinterpret_cast<const float4*>(q + b * DK)[lane];
    const int base = blockIdx.x * 32;
#pragma unroll
    for (int t = 0; t < 8; ++t) {
        const int tok = base + wave + 4 * t;
        const float4 tf =
            reinterpret_cast<const float4*>(tape + ((size_t)b * NUM_TAPE + tok) * FEATURES)[lane];
        float s = qf.x * tf.x + qf.y * tf.y + qf.z * tf.z + qf.w * tf.w;
#pragma unroll
        for (int off = 32; off; off >>= 1) s += __shfl_xor(s, off);
        if (lane == 0) scores[b * NUM_TAPE + tok] = s;
    }
}

// ---------------- Kernel B: per-batch radix-select top-k + softmax + scalars --------
__global__ __launch_bounds__(512) void k_topk(const float* __restrict__ scores,
                                              const float* __restrict__ mask_in,
                                              const float* __restrict__ hp_in,
                                              const float* __restrict__ rem_in,
                                              const float* __restrict__ nup_in,
                                              int* __restrict__ topk_ws,
                                              float* __restrict__ weights_ws,
                                              float* __restrict__ out) {
    const int b = blockIdx.x;
    const int tid = threadIdx.x;
    const int lane = tid & 63;
    const int wv = tid >> 6;
    __shared__ int hist[256];
    __shared__ int chunkTot[4];
    __shared__ int sh_digit, sh_hi;
    __shared__ int sel_idx[TOPK];
    __shared__ unsigned sel_key[TOPK];
    __shared__ float redf[8];
    __shared__ int tie_idx[TIECAP];
    __shared__ int tie_cnt, sel_cnt;
    __shared__ int in16_idx[TOP16];

    // 4 elements per thread, float4-coalesced: e = 4*tid + j
    const float4 sc = reinterpret_cast<const float4*>(scores + (size_t)b * NUM_TAPE)[tid];
    const float4 mk = reinterpret_cast<const float4*>(mask_in + (size_t)b * NUM_TAPE)[tid];
    unsigned key[4];
    key[0] = f2key(sc.x - mk.x * 1e9f);
    key[1] = f2key(sc.y - mk.y * 1e9f);
    key[2] = f2key(sc.z - mk.z * 1e9f);
    key[3] = f2key(sc.w - mk.w * 1e9f);

    // ---- radix select 1: k = 512 over 2048 keys
    unsigned prefix = 0;
    int krem = TOPK;
#pragma unroll
    for (int p = 0; p < 4; ++p) {
        const int shift = 24 - 8 * p;
        if (tid < 256) hist[tid] = 0;
        __syncthreads();
#pragma unroll
        for (int i = 0; i < 4; ++i) {
            const unsigned kk = key[i];
            const bool act = (p == 0) || ((kk >> (shift + 8)) == (prefix >> (shift + 8)));
            if (act) atomicAdd(&hist[(kk >> shift) & 0xFF], 1);
        }
        __syncthreads();
        int v = 0, hcnt = 0;
        if (tid < 256) {
            hcnt = hist[tid];
            v = hcnt;
#pragma unroll
            for (int off = 1; off < 64; off <<= 1) {
                const int t = __shfl_down(v, off);
                if (lane + off < 64) v += t;
            }
            if (lane == 0) chunkTot[wv] = v;
        }
        __syncthreads();
        if (tid < 256) {
#pragma unroll
            for (int w2 = 0; w2 < 4; ++w2)
                if (w2 > wv) v += chunkTot[w2];
            if (v >= krem && (v - hcnt) < krem) {
                sh_digit = tid;
                sh_hi = v - hcnt;
            }
        }
        __syncthreads();
        prefix |= ((unsigned)sh_digit) << shift;
        krem -= sh_hi;
        __syncthreads();
    }
    const unsigned T512 = prefix;
    const int krem512 = krem;

    // ---- compaction: key > T512 plus first krem512 ties (ascending index)
    if (tid == 0) {
        sel_cnt = 0;
        tie_cnt = 0;
    }
    __syncthreads();
#pragma unroll
    for (int i = 0; i < 4; ++i) {
        const int e = 4 * tid + i;
        const unsigned kk = key[i];
        if (kk > T512) {
            const int p = atomicAdd(&sel_cnt, 1);
            sel_idx[p] = e;
            sel_key[p] = kk;
        } else if (kk == T512) {
            const int p = atomicAdd(&tie_cnt, 1);
            if (p < TIECAP) tie_idx[p] = e;
        }
    }
    __syncthreads();
    int tc = tie_cnt < TIECAP ? tie_cnt : TIECAP;
    for (int t = tid; t < tc; t += 512) {
        const int my = tie_idx[t];
        int rank = 0;
        for (int u = 0; u < tc; ++u) rank += (tie_idx[u] < my);
        if (rank < krem512) {
            const int p = atomicAdd(&sel_cnt, 1);
            sel_idx[p] = my;
            sel_key[p] = T512;
        }
    }
    __syncthreads();

    // ---- radix select 2: k = 16 over the 512 selected keys (1/thread)
    const unsigned kk2 = sel_key[tid];
    prefix = 0;
    krem = TOP16;
#pragma unroll
    for (int p = 0; p < 4; ++p) {
        const int shift = 24 - 8 * p;
        if (tid < 256) hist[tid] = 0;
        __syncthreads();
        {
            const bool act = (p == 0) || ((kk2 >> (shift + 8)) == (prefix >> (shift + 8)));
            if (act) atomicAdd(&hist[(kk2 >> shift) & 0xFF], 1);
        }
        __syncthreads();
        int v = 0, hcnt = 0;
        if (tid < 256) {
            hcnt = hist[tid];
            v = hcnt;
#pragma unroll
            for (int off = 1; off < 64; off <<= 1) {
                const int t = __shfl_down(v, off);
                if (lane + off < 64) v += t;
            }
            if (lane == 0) chunkTot[wv] = v;
        }
        __syncthreads();
        if (tid < 256) {
#pragma unroll
            for (int w2 = 0; w2 < 4; ++w2)
                if (w2 > wv) v += chunkTot[w2];
            if (v >= krem && (v - hcnt) < krem) {
                sh_digit = tid;
                sh_hi = v - hcnt;
            }
        }
        __syncthreads();
        prefix |= ((unsigned)sh_digit) << shift;
        krem -= sh_hi;
        __syncthreads();
    }
    const unsigned T16 = prefix;
    const int krem16 = krem;

    // ---- top16 boundary-tie membership (ascending original index)
    if (tid == 0) tie_cnt = 0;
    __syncthreads();
    if (kk2 == T16) {
        const int p = atomicAdd(&tie_cnt, 1);
        if (p < TIECAP) tie_idx[p] = sel_idx[tid];
    }
    __syncthreads();
    tc = tie_cnt < TIECAP ? tie_cnt : TIECAP;
    for (int t = tid; t < tc; t += 512) {
        const int my = tie_idx[t];
        int rank = 0;
        for (int u = 0; u < tc; ++u) rank += (tie_idx[u] < my);
        if (rank < krem16) in16_idx[rank] = my;
    }
    __syncthreads();

    // ---- softmax over row-0 scores at selected idx (jnp.take flatten semantics)
    const int myidx = sel_idx[tid];
    const float wraw = scores[myidx] * 0.0625f; // scores[0, idx] / sqrt(256)

    float m = wraw;
#pragma unroll
    for (int off = 32; off; off >>= 1) m = fmaxf(m, __shfl_xor(m, off));
    if (lane == 0) redf[wv] = m;
    __syncthreads();
#pragma unroll
    for (int w2 = 0; w2 < 8; ++w2) m = fmaxf(m, redf[w2]);
    __syncthreads();

    const float e = expf(wraw - m);
    float s = e;
#pragma unroll
    for (int off = 32; off; off >>= 1) s += __shfl_xor(s, off);
    if (lane == 0) redf[wv] = s;
    __syncthreads();
    s = 0.f;
#pragma unroll
    for (int w2 = 0; w2 < 8; ++w2) s += redf[w2];
    __syncthreads();

    const float w = e / s;
    weights_ws[b * TOPK + tid] = w;
    topk_ws[b * TOPK + tid] = myidx;

    float lsq = w * w;
#pragma unroll
    for (int off = 32; off; off >>= 1) lsq += __shfl_xor(lsq, off);
    if (lane == 0) redf[wv] = lsq;
    __syncthreads();
    float sumsq = 0.f;
#pragma unroll
    for (int w2 = 0; w2 < 8; ++w2) sumsq += redf[w2];
    __syncthreads();

    bool in16 = (kk2 > T16);
    if (kk2 == T16) {
        for (int u = 0; u < krem16; ++u)
            if (in16_idx[u] == myidx) in16 = true;
    }
    float l16 = in16 ? w : 0.f;
#pragma unroll
    for (int off = 32; off; off >>= 1) l16 += __shfl_xor(l16, off);
    if (lane == 0) redf[wv] = l16;
    __syncthreads();
    float s16 = 0.f;
#pragma unroll
    for (int w2 = 0; w2 < 8; ++w2) s16 += redf[w2];

    if (tid == 0) {
        const float hp = hp_in[b], rem = rem_in[b], nup = nup_in[b];
        const float entropy = 1.0f - sumsq;
        const float still = (hp < THRESH) ? 1.f : 0.f;
        const float nh = ((hp + s16) >= THRESH ? 1.f : 0.f) * still;
        const float st2 = still - nh;
        out[OFF_REM + b] = rem + (nh + st2) * entropy;
        float hp1 = hp + s16 * st2;
        hp1 = hp1 + nh * (THRESH - hp1);
        out[OFF_HP + b] = hp1;
        out[OFF_NUP + b] = nup + st2 + nh;
    }

    // score_mask: copy row (we already hold it as mk), then +1 at selected
    reinterpret_cast<float4*>(out + OFF_MASK + (size_t)b * NUM_TAPE)[tid] = mk;
    __syncthreads();
    out[OFF_MASK + b * NUM_TAPE + myidx] = mask_in[b * NUM_TAPE + myidx] + 1.0f;
}

// ---------------- Kernel C: partial weighted sums over k-chunks (float4) ------------
__global__ __launch_bounds__(512) void k_gather(const float* __restrict__ tape,
                                                const int* __restrict__ topk_ws,
                                                const float* __restrict__ weights_ws,
                                                float* __restrict__ partials) {
    const int b = blockIdx.y;
    const int kc = blockIdx.x;
    const int rs = threadIdx.x >> 7;   // 0..3 row-subgroup
    const int f4 = threadIdx.x & 127;  // float4 feature index
    __shared__ float wsh[KPER];
    __shared__ int ish[KPER];
    __shared__ float4 shacc[512];
    if (threadIdx.x < KPER) {
        wsh[threadIdx.x] = weights_ws[b * TOPK + kc * KPER + threadIdx.x];
        ish[threadIdx.x] = topk_ws[b * TOPK + kc * KPER + threadIdx.x];
    }
    __syncthreads();
    float4 acc = {0.f, 0.f, 0.f, 0.f};
#pragma unroll 4
    for (int k = rs; k < KPER; k += 4) {
        const float w = wsh[k];
        const float4 t =
            reinterpret_cast<const float4*>(tape + ((size_t)b * NUM_TAPE + ish[k]) * FEATURES)[f4];
        acc.x = fmaf(w, t.x, acc.x);
        acc.y = fmaf(w, t.y, acc.y);
        acc.z = fmaf(w, t.z, acc.z);
        acc.w = fmaf(w, t.w, acc.w);
    }
    shacc[threadIdx.x] = acc;
    __syncthreads();
    if (threadIdx.x < 128) {
        const float4 a0 = shacc[f4];
        const float4 a1 = shacc[128 + f4];
        const float4 a2 = shacc[256 + f4];
        const float4 a3 = shacc[384 + f4];
        float4 r;
        r.x = (a0.x + a1.x) + (a2.x + a3.x);
        r.y = (a0.y + a1.y) + (a2.y + a3.y);
        r.z = (a0.z + a1.z) + (a2.z + a3.z);
        r.w = (a0.w + a1.w) + (a2.w + a3.w);
        reinterpret_cast<float4*>(partials + ((size_t)b * KCHUNKS + kc) * FEATURES)[f4] = r;
    }
}

// ---------------- Kernel D: reduce partials -> token_sel + query update ------------
__global__ __launch_bounds__(512) void k_finish(const float* __restrict__ q,
                                                const float* __restrict__ partials,
                                                float* __restrict__ out) {
    const int b = blockIdx.x;
    const int g = threadIdx.x >> 7;    // 0..3
    const int f4 = threadIdx.x & 127;  // float4 feature index
    __shared__ float4 sh[512];
    const float4* pp = reinterpret_cast<const float4*>(partials + (size_t)b * KCHUNKS * FEATURES);
    const float4 a = pp[g * 128 + f4];
    const float4 c = pp[(g + 4) * 128 + f4];
    float4 r;
    r.x = a.x + c.x;
    r.y = a.y + c.y;
    r.z = a.z + c.z;
    r.w = a.w + c.w;
    sh[threadIdx.x] = r;
    __syncthreads();
    if (threadIdx.x < 128) {
        const float4 s0 = sh[f4];
        const float4 s1 = sh[128 + f4];
        const float4 s2 = sh[256 + f4];
        const float4 s3 = sh[384 + f4];
        float4 s;
        s.x = (s0.x + s1.x) + (s2.x + s3.x);
        s.y = (s0.y + s1.y) + (s2.y + s3.y);
        s.z = (s0.z + s1.z) + (s2.z + s3.z);
        s.w = (s0.w + s1.w) + (s2.w + s3.w);
        reinterpret_cast<float4*>(out + OFF_TSEL + (size_t)b * FEATURES)[f4] = s;
        if (f4 < 64) {
            const float4 qv = reinterpret_cast<const float4*>(q + (size_t)b * DK)[f4];
            float4 nq;
            nq.x = (qv.x + s.x) * 0.5f;
            nq.y = (qv.y + s.y) * 0.5f;
            nq.z = (qv.z + s.z) * 0.5f;
            nq.w = (qv.w + s.w) * 0.5f;
            reinterpret_cast<float4*>(out + OFF_Q + (size_t)b * DK)[f4] = nq;
        }
    }
}

extern "C" void kernel_launch(void* const* d_in, const int* in_sizes, int n_in,
                              void* d_out, int out_size, void* d_ws, size_t ws_size,
                              hipStream_t stream) {
    const float* q = (const float*)d_in[0];
    const float* hp = (const float*)d_in[1];
    const float* rem = (const float*)d_in[2];
    const float* nup = (const float*)d_in[3];
    const float* mask = (const float*)d_in[4];
    const float* tape = (const float*)d_in[5];
    float* out = (float*)d_out;
    float* ws = (float*)d_ws;

    float* scores = ws + WS_SCORES;
    int* topk = (int*)(ws + WS_TOPK);
    float* weights = ws + WS_WEIGHTS;
    float* partials = ws + WS_PART;

    k_scores<<<dim3(NUM_TAPE / 32, BATCH), 256, 0, stream>>>(q, tape, scores);
    k_topk<<<BATCH, 512, 0, stream>>>(scores, mask, hp, rem, nup, topk, weights, out);
    k_gather<<<dim3(KCHUNKS, BATCH), 512, 0, stream>>>(tape, topk, weights, partials);
    k_finish<<<BATCH, 512, 0, stream>>>(q, partials, out);
}